// Round 10
// baseline (776.796 us; speedup 1.0000x reference)
//
#include <hip/hip_runtime.h>
#include <math.h>

// Fused semantic attention — round-8 skeleton + 1-barrier/chunk software pipeline.
// (Round-10 = round-9 with the cvt_pkrtz type fix: the builtin returns
//  __fp16 ext_vector(2), which clang won't assign to a _Float16 vector.)
// Changes vs round 8 (cadence attack; traffic already clean at ~650 MB):
//  - S consumption lags one chunk: window kc = QK(kc) || PROC(kc-1) || stage(kc+1),
//    ONE barrier per chunk (33 -> 17 windows). Sst double-, Vt triple-buffered.
//  - all f32->f16 packs via v_cvt_pkrtz (half the cvt instructions)
//  - exp as exp2(fma(s, log2e, -12*log2e)) (drops __expf's extra mul)
//  - out_a epilogue unchanged: replay own 128 KB out_s slice from L2 (round-8 win)
// LDS: Kb 17.4K + Vt 26.1K + Sst 17.4K + rsum ~= 61 KB -> 2 blocks/CU.

#define BH 64
#define N 1024
#define D 64
#define TK 64
#define NC (N / TK)   // 16
#define KSTR 68       // f16 row stride: 2-way max on b128 reads (proven ~65K confl)
#define SSTR 68       // f32 row stride
#define LOG2E 1.44269504088896f
#define ESHIFT (-17.3123404907f)   // -12 * log2(e)

typedef float    f32x4 __attribute__((ext_vector_type(4)));
typedef _Float16 half8 __attribute__((ext_vector_type(8)));
typedef _Float16 half4 __attribute__((ext_vector_type(4)));
typedef __fp16   fp16x2 __attribute__((ext_vector_type(2)));  // cvt_pkrtz result type

__global__ __launch_bounds__(512, 2) void attn_fused_kernel(
    const float* __restrict__ q, const float* __restrict__ k,
    const float* __restrict__ v, const float* __restrict__ qs,
    const float* __restrict__ ks, float* __restrict__ out_o,
    float* __restrict__ out_a, float* __restrict__ out_s)
{
    __shared__ __align__(16) _Float16 Kb[2][TK][KSTR];   // fused K chunk, dbuf
    __shared__ __align__(16) _Float16 Vt[3][D][KSTR];    // V^T chunk, tri-buf
    __shared__ __align__(16) float    Sst[2][32][SSTR];  // S staging, dbuf
    __shared__ float rsumf[32];

    const int t  = threadIdx.x;
    const int w  = t >> 6;
    const int l  = t & 63;
    const int lr = l & 15;
    const int lg = l >> 4;
    const int qt = w >> 2;     // q 16-row tile
    const int kt = w & 3;      // QK: k 16-col tile; PV: d 16-col tile

    // XCD pinning: wg%8 == XCD; 32 q-tiles of one batch share one XCD's L2.
    const int wg = blockIdx.x;
    const int b  = ((wg >> 8) << 3) | (wg & 7);
    const int q0 = ((wg >> 3) & 31) * 32;

    const size_t inb = (size_t)b * (N * D);
    const size_t sb  = (size_t)b * N * N + (size_t)q0 * N;

    // ---- Q fragment (A-operand rows = q0+qt*16+lr), pkrtz packs ----
    half8 qa[2];
    {
        const float* qp  = q  + inb + (size_t)(q0 + qt * 16 + lr) * D + lg * 8;
        const float* qsp = qs + inb + (size_t)(q0 + qt * 16 + lr) * D + lg * 8;
#pragma unroll
        for (int kst = 0; kst < 2; ++kst) {
            f32x4 a0 = *(const f32x4*)(qp + kst * 32);
            f32x4 a1 = *(const f32x4*)(qp + kst * 32 + 4);
            f32x4 c0 = *(const f32x4*)(qsp + kst * 32);
            f32x4 c1 = *(const f32x4*)(qsp + kst * 32 + 4);
            f32x4 s0 = a0 + c0, s1 = a1 + c1;
            union { half8 h8; fp16x2 h2[4]; } u;
            u.h2[0] = __builtin_amdgcn_cvt_pkrtz(s0[0], s0[1]);
            u.h2[1] = __builtin_amdgcn_cvt_pkrtz(s0[2], s0[3]);
            u.h2[2] = __builtin_amdgcn_cvt_pkrtz(s1[0], s1[1]);
            u.h2[3] = __builtin_amdgcn_cvt_pkrtz(s1[2], s1[3]);
            qa[kst] = u.h8;
        }
    }

    // ---- staging: waves 0-3 load K+KS, waves 4-7 load V (wave-uniform) ----
    const int  ts = t & 255;
    const bool kstager = (w < 4);
    f32x4 kreg[4], sreg[4], vreg[4];

    auto LOAD = [&](int kc) {   // every instr: 1KB contiguous per wave-group
        if (kstager) {
            const f32x4* kbp = (const f32x4*)(k  + inb + (size_t)kc * TK * D);
            const f32x4* sbp = (const f32x4*)(ks + inb + (size_t)kc * TK * D);
#pragma unroll
            for (int j = 0; j < 4; ++j) {
                kreg[j] = kbp[j * 256 + ts];
                sreg[j] = sbp[j * 256 + ts];
            }
        } else {
            const f32x4* vbp = (const f32x4*)(v + inb + (size_t)kc * TK * D);
#pragma unroll
            for (int j = 0; j < 4; ++j)
                vreg[j] = vbp[((ts >> 4) * 4 + j) * 16 + (ts & 15)];
        }
    };
    auto STORE = [&](int kbf, int vbf) {
        if (kstager) {          // fused Kf row-major, pkrtz packs
#pragma unroll
            for (int j = 0; j < 4; ++j) {
                const int row = j * 16 + (ts >> 4), col = (ts & 15) * 4;
                f32x4 sm = kreg[j] + sreg[j];
                union { half4 h4; fp16x2 h2[2]; } u;
                u.h2[0] = __builtin_amdgcn_cvt_pkrtz(sm[0], sm[1]);
                u.h2[1] = __builtin_amdgcn_cvt_pkrtz(sm[2], sm[3]);
                *(half4*)&Kb[kbf][row][col] = u.h4;
            }
        } else {                // V 4x4 register transpose -> Vt[d][kk]
            const int br4 = (ts >> 4) * 4, bc4 = (ts & 15) * 4;
#pragma unroll
            for (int c = 0; c < 4; ++c) {
                union { half4 h4; fp16x2 h2[2]; } u;
                u.h2[0] = __builtin_amdgcn_cvt_pkrtz(vreg[0][c], vreg[1][c]);
                u.h2[1] = __builtin_amdgcn_cvt_pkrtz(vreg[2][c], vreg[3][c]);
                *(half4*)&Vt[vbf][bc4 + c][br4] = u.h4;
            }
        }
    };

    f32x4 oacc = {0.f, 0.f, 0.f, 0.f};
    float rs = 0.0f;

    // PROC(j): out_s store + exp + PV for chunk j (reads Sst[j&1], Vt[j%3])
    auto PROC = [&](int j) {
        const int sbf = j & 1, vbf = j % 3;
        {   // out_s: cacheable coalesced (L2-resident for the epilogue replay)
            f32x4 sv = *(const f32x4*)&Sst[sbf][t >> 4][(t & 15) * 4];
            *(f32x4*)(out_s + sb + (size_t)(t >> 4) * N + j * TK + (t & 15) * 4) = sv;
        }
#pragma unroll
        for (int kst = 0; kst < 2; ++kst) {
            f32x4 s0 = *(const f32x4*)&Sst[sbf][qt * 16 + lr][kst * 32 + lg * 8];
            f32x4 s1 = *(const f32x4*)&Sst[sbf][qt * 16 + lr][kst * 32 + lg * 8 + 4];
            float e[8];
#pragma unroll
            for (int i = 0; i < 4; ++i) {
                e[i]     = __builtin_amdgcn_exp2f(__builtin_fmaf(s0[i], LOG2E, ESHIFT));
                e[i + 4] = __builtin_amdgcn_exp2f(__builtin_fmaf(s1[i], LOG2E, ESHIFT));
            }
            if (kt == 0)
                rs += ((e[0] + e[1]) + (e[2] + e[3])) + ((e[4] + e[5]) + (e[6] + e[7]));
            union { half8 h8; fp16x2 h2[4]; } u;
            u.h2[0] = __builtin_amdgcn_cvt_pkrtz(e[0], e[1]);
            u.h2[1] = __builtin_amdgcn_cvt_pkrtz(e[2], e[3]);
            u.h2[2] = __builtin_amdgcn_cvt_pkrtz(e[4], e[5]);
            u.h2[3] = __builtin_amdgcn_cvt_pkrtz(e[6], e[7]);
            half8 vb = *(const half8*)&Vt[vbf][kt * 16 + lr][kst * 32 + lg * 8];
            oacc = __builtin_amdgcn_mfma_f32_16x16x32_f16(u.h8, vb, oacc, 0, 0, 0);
        }
    };

    // ---- prologue: stage chunk 0 ----
    LOAD(0);
    STORE(0, 0);
    __syncthreads();

    // ---- main loop: 1 barrier per chunk ----
    for (int kc = 0; kc < NC; ++kc) {
        if (kc + 1 < NC) LOAD(kc + 1);

        {   // QK(kc) -> Sst[kc&1]
            const int c = kc & 1;
            half8 kb0 = *(const half8*)&Kb[c][kt * 16 + lr][lg * 8];
            half8 kb1 = *(const half8*)&Kb[c][kt * 16 + lr][32 + lg * 8];
            f32x4 ac = {0.f, 0.f, 0.f, 0.f};
            ac = __builtin_amdgcn_mfma_f32_16x16x32_f16(qa[0], kb0, ac, 0, 0, 0);
            ac = __builtin_amdgcn_mfma_f32_16x16x32_f16(qa[1], kb1, ac, 0, 0, 0);
#pragma unroll
            for (int r = 0; r < 4; ++r)   // C/D: col=lr, row=4*lg+r
                Sst[c][qt * 16 + lg * 4 + r][kt * 16 + lr] = ac[r] * 0.125f;
        }

        if (kc > 0) PROC(kc - 1);                       // consume previous chunk
        if (kc + 1 < NC) STORE((kc + 1) & 1, (kc + 1) % 3);
        __syncthreads();
        // hazards: Sst[c] last read by PROC(kc-2) [prev window]; Kb[(kc+1)&1]
        // last read by QK(kc-1) [prev window]; Vt[(kc+1)%3] last read by
        // PROC(kc-2) [prev window] -- all barrier-separated.
    }
    PROC(NC - 1);   // tail: Sst[(NC-1)&1], Vt[(NC-1)%3]; no writers after

    // ---- rowsum finalize (kt==0 waves hold lg-group partials) ----
    if (kt == 0) {
        rs += __shfl_xor(rs, 16);
        rs += __shfl_xor(rs, 32);
        if (l < 16) rsumf[qt * 16 + l] = rs;
    }
    __syncthreads();
    if (t < 32) rsumf[t] = 1.0f / rsumf[t];
    __syncthreads();

    // ---- O: scale into Sst[0], coalesced NT store ----
#pragma unroll
    for (int r = 0; r < 4; ++r)
        Sst[0][qt * 16 + lg * 4 + r][kt * 16 + lr] =
            oacc[r] * rsumf[qt * 16 + lg * 4 + r];
    __syncthreads();
    {
        f32x4 ov = *(const f32x4*)&Sst[0][t >> 4][(t & 15) * 4];
        __builtin_nontemporal_store(ov,
            (f32x4*)(out_o + inb + (size_t)(q0 + (t >> 4)) * D + (t & 15) * 4));
    }

    // ---- out_a epilogue: replay own out_s slice (L2-hot), exp*inv, NT store ----
    {
        const int   arow = t >> 4;
        const int   ac0  = (t & 15) * 4;
        const float iva  = rsumf[arow];
        const float* sp  = out_s + sb + (size_t)arow * N + ac0;
        float*       ap  = out_a + sb + (size_t)arow * N + ac0;
#pragma unroll 4
        for (int cb = 0; cb < NC; ++cb) {
            f32x4 sv = *(const f32x4*)(sp + cb * TK);
            f32x4 av;
#pragma unroll
            for (int i = 0; i < 4; ++i)
                av[i] = __builtin_amdgcn_exp2f(__builtin_fmaf(sv[i], LOG2E, ESHIFT)) * iva;
            __builtin_nontemporal_store(av, (f32x4*)(ap + cb * TK));
        }
    }
}

extern "C" void kernel_launch(void* const* d_in, const int* in_sizes, int n_in,
                              void* d_out, int out_size, void* d_ws, size_t ws_size,
                              hipStream_t stream) {
    const float* q  = (const float*)d_in[0];
    const float* k  = (const float*)d_in[1];
    const float* v  = (const float*)d_in[2];
    const float* qs = (const float*)d_in[3];
    const float* ks = (const float*)d_in[4];

    float* out_o = (float*)d_out;                       // [64,1024,64]
    float* out_a = out_o + (size_t)BH * N * D;          // [64,1024,1024]
    float* out_s = out_a + (size_t)BH * N * N;          // [64,1024,1024]

    attn_fused_kernel<<<dim3(BH * (N / 32)), dim3(512), 0, stream>>>(
        q, k, v, qs, ks, out_o, out_a, out_s);
}